// Round 18
// baseline (152.550 us; speedup 1.0000x reference)
//
#include <hip/hip_runtime.h>
#include <stdint.h>

#define B_SZ 4096
#define D_SZ 512
#define SHIFT 64.0f

typedef __attribute__((ext_vector_type(4))) float floatx4;
typedef __attribute__((ext_vector_type(2))) long lng2;
typedef unsigned char u8;
typedef unsigned int u32;

#define GLD_LDS16(gp, sp)                                                              \
    __builtin_amdgcn_global_load_lds(                                                  \
        (const __attribute__((address_space(1))) void*)(gp),                           \
        (__attribute__((address_space(3))) void*)(sp), 16, 0, 0)

#define FP8MFMA(accv, av, bv)                                                          \
    accv = __builtin_amdgcn_mfma_f32_16x16x32_fp8_fp8(av, bv, accv, 0, 0, 0)

// ---- K1: fp32->fp8(e4m3) convert (K-interleaved layout) + per-row time,
//      fused: histogram (block 0), accumulator zeroing, entailment partials.
//      K-perm: within each 64B K-window, 8B group (h,c) -> slot c*2+h; applied
//      to BOTH operands => Grammian unchanged. ----
__global__ __launch_bounds__(256) void prep_kernel(
    const float* __restrict__ img, const float* __restrict__ dna,
    const float* __restrict__ txt, const float* __restrict__ curv_p,
    const int* __restrict__ labels, int* __restrict__ hist,
    u8* __restrict__ f8, float* __restrict__ times,
    float* __restrict__ zero_f, float* __restrict__ ent_partial) {
    __shared__ int lhist[512];
    __shared__ float red[4];
    int t = threadIdx.x;
    int gid = blockIdx.x * 256 + t;
    if (gid < 49155) zero_f[gid] = 0.0f;    // rsum/csum + ce_acc/ent_acc/done

    if (blockIdx.x == 0) {                  // label histogram, single block
        lhist[t] = 0; lhist[t + 256] = 0;
        __syncthreads();
        for (int n = t; n < B_SZ; n += 256) atomicAdd(&lhist[labels[n]], 1);
        __syncthreads();
        hist[t] = lhist[t]; hist[t + 256] = lhist[t + 256];
    }

    int wave = gid >> 6;  // 0..12287
    int lane = t & 63;
    const float* src = (wave < B_SZ) ? img : (wave < 2 * B_SZ) ? dna : txt;
    int row = wave & (B_SZ - 1);
    const float* p = src + row * D_SZ + lane * 8;
    float4 v0 = *(const float4*)(p);
    float4 v1 = *(const float4*)(p + 4);
    float ss = v0.x*v0.x + v0.y*v0.y + v0.z*v0.z + v0.w*v0.w
             + v1.x*v1.x + v1.y*v1.y + v1.z*v1.z + v1.w*v1.w;
    u32 w0 = __builtin_amdgcn_cvt_pk_fp8_f32(v0.x, v0.y, 0, false);
    w0 = __builtin_amdgcn_cvt_pk_fp8_f32(v0.z, v0.w, w0, true);
    u32 w1 = __builtin_amdgcn_cvt_pk_fp8_f32(v1.x, v1.y, 0, false);
    w1 = __builtin_amdgcn_cvt_pk_fp8_f32(v1.z, v1.w, w1, true);
    uint2 pk; pk.x = w0; pk.y = w1;
    // lane = 8B group: window lane>>3, half (lane>>2)&1, chunk lane&3
    int gperm = (lane & 56) | ((lane & 3) << 1) | ((lane >> 2) & 1);
    *(uint2*)(f8 + (size_t)wave * D_SZ + gperm * 8) = pk;

    bool isdna = (wave >= B_SZ) && (wave < 2 * B_SZ);
    float dot = 0.0f, ssy = 0.0f;
    if (isdna) {                            // matching image row for entailment
        const float* y = img + row * D_SZ + lane * 8;
        float4 y0 = *(const float4*)y, y1 = *(const float4*)(y + 4);
        dot = v0.x*y0.x + v0.y*y0.y + v0.z*y0.z + v0.w*y0.w
            + v1.x*y1.x + v1.y*y1.y + v1.z*y1.z + v1.w*y1.w;
        ssy = y0.x*y0.x + y0.y*y0.y + y0.z*y0.z + y0.w*y0.w
            + y1.x*y1.x + y1.y*y1.y + y1.z*y1.z + y1.w*y1.w;
    }
    #pragma unroll
    for (int m = 1; m < 64; m <<= 1) {
        ss += __shfl_xor(ss, m);
        if (isdna) { dot += __shfl_xor(dot, m); ssy += __shfl_xor(ssy, m); }
    }
    float curv = curv_p[0];
    float ep = 0.0f;
    if (lane == 0) {
        float xt = sqrtf(1.0f / curv + ss);
        times[wave] = xt;
        if (isdna) {
            float yt = sqrtf(1.0f / curv + ssy);
            float nx = sqrtf(ss);
            float c = curv * (dot - xt * yt);                      // <= -1
            float numer = yt + c * xt;
            float denom = nx * sqrtf(fmaxf(c * c - 1.0f, 0.0f));
            float ai = numer / (denom + 1e-8f);
            ai = fminf(fmaxf(ai, -1.0f + 1e-8f), 1.0f - 1e-8f);
            float ang = acosf(ai);
            float as_in = 0.2f / (nx * sqrtf(curv) + 1e-6f);       // 2*min_radius
            as_in = fminf(fmaxf(as_in, -1.0f + 1e-6f), 1.0f - 1e-6f);
            float ap = asinf(as_in);
            ep = fmaxf(ang - ap, 0.0f);
        }
    }
    if (blockIdx.x >= 1024 && blockIdx.x < 2048) {   // pure-dna blocks
        if (lane == 0) red[t >> 6] = ep;
        __syncthreads();
        if (t == 0) ent_partial[blockIdx.x - 1024] = red[0] + red[1] + red[2] + red[3];
    }
}

// ---- K2: batched fp8 MFMA GEMM (A·B^T), 128x128 tile, 8 waves, 32x64/wave.
//      R35 = R33 CHAMPION restored verbatim (total 148.3, gemm 74.5us).
//      R34's cooperative prep-fusion FAILED (absmax 79 == ref magnitude ->
//      cooperative launch likely never executed under graph capture, or
//      cross-XCD f8 visibility race across grid.sync; unverifiable headless
//      -> lever abandoned). The 2-launch structure stands.
//      Structure: persistent 512 blocks (exact 2/CU residency), 6 tiles
//      each + READ-AHEAD register pipeline: at step k, await stage(k+1),
//      issue stage(k+3) [dist-3, 4 buffers], read frags(k+1) into the
//      ALTERNATE named register set, MFMA on current set -- 6 ds_read_b128
//      (+~120cy latency) hide under the 16-MFMA cluster. Named sets per
//      rule #20 (no indexed arrays -> no scratch; VGPR 64, WRITE 36.9MB
//      verified clean R33).
//      Globally uniform schedule (stage(k) issued at step k-3; k=tile*8+si):
//        si=0..4: issue current-tile stage(si+3) -> buf[(si+3)&3]
//        si=5,6,7: issue NEXT-tile stage(0,1,2) -> buf[0,1,2]  (tile<5)
//        read-ahead at si reads buf[(si+1)&3]; si=7 reads next tile frags(0)
//      vmcnt ledger (2 GLD/stage, re-derive per geometry -- R29 lesson):
//      steady in-flight at step top = {k+1,k+2} = 4 -> vmcnt(2) awaits
//      stage(k+1) (in-order oldest-first, m135). Tile5 tail: si=6 ->
//      vmcnt(0); si=7 no read-ahead. Prologue: stages 0,1,2; vmcnt(4);
//      barrier; read frags(0) -> E set.
//      Ledger: R34 coop fusion failed. R33 = 148.3 champion. R32=R30 150-151.
//      R31 fused finalize regressed (serial tail). R29 vmcnt bug. R28/R19
//      256^2 spill (allocator pins 128 VGPR @512thr; dead). R27 256thr VGPR
//      pin. R26 reg-dbuf spill. R25 dist-3+setprio regressed. R24 counted-
//      vmcnt dist-2 win (88.5). R23 XCD remap, R22 direct-L2, R20 4-phase,
//      R18 min-waves pin, R15 threadfence: all regressions.
__global__ __launch_bounds__(512, 4) void gemm_epi_kernel(
    const u8* __restrict__ f8, const float* __restrict__ times,
    const int* __restrict__ labels,
    const float* __restrict__ ls_p, const float* __restrict__ curv_p,
    float* __restrict__ rsum_e, float* __restrict__ rsum_t,
    float* __restrict__ csum_e, float* __restrict__ csum_t) {
    __shared__ u8 sA[4][128 * 64];    // 32 KB
    __shared__ u8 sB[4][128 * 64];    // 32 KB -> 64 KB total, 2 blocks/CU

    int t = threadIdx.x;
    int wave = t >> 6, lane = t & 63;
    int wr = wave >> 1;                   // row 32-group (0..3)
    int wc = wave & 1;                    // col 64-group (0..1)
    int chunk = (t & 3) ^ ((t >> 3) & 3);
    int q = lane >> 4, s = lane & 15;
    int slot16 = (q ^ ((s >> 1) & 3)) << 4;
    int aBase = (wr * 32 + s) * 64 + slot16;     // + ii*1024 per fragment
    int bBase = (wc * 64 + s) * 64 + slot16;     // + j*1024 per fragment

    float ls = ls_p[0];
    float curv = curv_p[0];
    float rsc = rsqrtf(curv);
    float c2 = -ls * rsc;
    float c1 = c2 * 0.69314718f;
    float sh2p = SHIFT * 1.44269504f + c2;

    // named frag register sets (rule #20: no indexed arrays -> no scratch)
    lng2 eA0, eA1, eB0, eB1, eB2, eB3;    // even-step set
    lng2 oA0, oA1, oB0, oB1, oB2, oB3;    // odd-step set

#define TILE_PTRS(TL, GAV, GBV)                                                        \
    {                                                                                  \
        int z_ = (TL) >> 10;                                                           \
        int rem_ = (TL) & 1023;                                                        \
        int pa_ = (z_ == 2) ? 1 : 0;                                                   \
        int pb_ = (z_ == 0) ? 1 : 2;                                                   \
        GAV = f8 + (size_t)pa_ * (B_SZ * D_SZ)                                         \
            + (size_t)(((rem_ >> 5) * 128) + (t >> 2)) * D_SZ + chunk * 16;            \
        GBV = f8 + (size_t)pb_ * (B_SZ * D_SZ)                                         \
            + (size_t)(((rem_ & 31) * 128) + (t >> 2)) * D_SZ + chunk * 16;            \
    }

#define KSTEP(SI, CUR, NXT, ISSUE_COND, PTRA, PTRB, VW2, DO_READ)                      \
    do {                                                                               \
        asm volatile("s_waitcnt lgkmcnt(0)" ::: "memory");                             \
        if (VW2) { asm volatile("s_waitcnt vmcnt(2)" ::: "memory"); }                  \
        else     { asm volatile("s_waitcnt vmcnt(0)" ::: "memory"); }                  \
        asm volatile("s_barrier" ::: "memory");                                        \
        if (ISSUE_COND) {                                                              \
            GLD_LDS16((PTRA), &sA[(SI + 3) & 3][wave * 1024]);                         \
            GLD_LDS16((PTRB), &sB[(SI + 3) & 3][wave * 1024]);                         \
        }                                                                              \
        if (DO_READ) {                                                                 \
            const u8* pA_ = &sA[(SI + 1) & 3][0];                                      \
            const u8* pB_ = &sB[(SI + 1) & 3][0];                                      \
            NXT##A0 = *(const lng2*)(pA_ + aBase);                                     \
            NXT##A1 = *(const lng2*)(pA_ + aBase + 1024);                              \
            NXT##B0 = *(const lng2*)(pB_ + bBase);                                     \
            NXT##B1 = *(const lng2*)(pB_ + bBase + 1024);                              \
            NXT##B2 = *(const lng2*)(pB_ + bBase + 2048);                              \
            NXT##B3 = *(const lng2*)(pB_ + bBase + 3072);                              \
        }                                                                              \
        FP8MFMA(acc[0][0], CUR##A0.x, CUR##B0.x);                                      \
        FP8MFMA(acc[0][1], CUR##A0.x, CUR##B1.x);                                      \
        FP8MFMA(acc[0][2], CUR##A0.x, CUR##B2.x);                                      \
        FP8MFMA(acc[0][3], CUR##A0.x, CUR##B3.x);                                      \
        FP8MFMA(acc[1][0], CUR##A1.x, CUR##B0.x);                                      \
        FP8MFMA(acc[1][1], CUR##A1.x, CUR##B1.x);                                      \
        FP8MFMA(acc[1][2], CUR##A1.x, CUR##B2.x);                                      \
        FP8MFMA(acc[1][3], CUR##A1.x, CUR##B3.x);                                      \
        FP8MFMA(acc[0][0], CUR##A0.y, CUR##B0.y);                                      \
        FP8MFMA(acc[0][1], CUR##A0.y, CUR##B1.y);                                      \
        FP8MFMA(acc[0][2], CUR##A0.y, CUR##B2.y);                                      \
        FP8MFMA(acc[0][3], CUR##A0.y, CUR##B3.y);                                      \
        FP8MFMA(acc[1][0], CUR##A1.y, CUR##B0.y);                                      \
        FP8MFMA(acc[1][1], CUR##A1.y, CUR##B1.y);                                      \
        FP8MFMA(acc[1][2], CUR##A1.y, CUR##B2.y);                                      \
        FP8MFMA(acc[1][3], CUR##A1.y, CUR##B3.y);                                      \
    } while (0)

    // ---- prologue (tile 0): stage K-steps 0,1,2; read frags(0) -> E ----
    const u8* gA;  const u8* gB;
    TILE_PTRS(blockIdx.x * 6, gA, gB);
    GLD_LDS16(gA,       &sA[0][wave * 1024]);
    GLD_LDS16(gB,       &sB[0][wave * 1024]);
    GLD_LDS16(gA + 64,  &sA[1][wave * 1024]);
    GLD_LDS16(gB + 64,  &sB[1][wave * 1024]);
    GLD_LDS16(gA + 128, &sA[2][wave * 1024]);
    GLD_LDS16(gB + 128, &sB[2][wave * 1024]);
    asm volatile("s_waitcnt vmcnt(4)" ::: "memory");   // stage(0) landed
    asm volatile("s_barrier" ::: "memory");
    eA0 = *(const lng2*)(&sA[0][0] + aBase);
    eA1 = *(const lng2*)(&sA[0][0] + aBase + 1024);
    eB0 = *(const lng2*)(&sB[0][0] + bBase);
    eB1 = *(const lng2*)(&sB[0][0] + bBase + 1024);
    eB2 = *(const lng2*)(&sB[0][0] + bBase + 2048);
    eB3 = *(const lng2*)(&sB[0][0] + bBase + 3072);

    #pragma unroll 1
    for (int tile = 0; tile < 6; ++tile) {
        int tl = blockIdx.x * 6 + tile;           // 0..3071
        int z   = tl >> 10;
        int rem = tl & 1023;
        int rowBlk = (rem >> 5) * 128;
        int colBlk = (rem & 31) * 128;
        int pa = (z == 2) ? 1 : 0;
        int pb = (z == 0) ? 1 : 2;
        TILE_PTRS(tl, gA, gB);
        const u8* gAx;  const u8* gBx;            // next tile (guarded by nt)
        TILE_PTRS((tl + 1 < 3072) ? (tl + 1) : 0, gAx, gBx);
        bool nt = (tile < 5);

        floatx4 acc[2][4];
        #pragma unroll
        for (int ii = 0; ii < 2; ++ii)
            #pragma unroll
            for (int j = 0; j < 4; ++j) acc[ii][j] = (floatx4){0.f, 0.f, 0.f, 0.f};

        KSTEP(0, e, o, true, gA + 3 * 64, gB + 3 * 64, true, true);
        KSTEP(1, o, e, true, gA + 4 * 64, gB + 4 * 64, true, true);
        KSTEP(2, e, o, true, gA + 5 * 64, gB + 5 * 64, true, true);
        KSTEP(3, o, e, true, gA + 6 * 64, gB + 6 * 64, true, true);
        KSTEP(4, e, o, true, gA + 7 * 64, gB + 7 * 64, true, true);
        KSTEP(5, o, e, nt,   gAx,         gBx,         true, true);
        KSTEP(6, e, o, nt,   gAx + 64,    gBx + 64,    nt,   true);
        KSTEP(7, o, e, nt,   gAx + 128,   gBx + 128,   nt,   nt);

        // ---- slim fused epilogue (verified R7-R33, unchanged); runs with
        //      next tile's staging loads in flight. ----
        const float* tA = times + pa * B_SZ;
        const float* tB = times + pb * B_SZ;
        int rowbase = rowBlk + wr * 32;
        int colbase = colBlk + wc * 64;

        float tb[4]; int lb[4]; int mcol[4];
        #pragma unroll
        for (int j = 0; j < 4; ++j) {
            mcol[j] = colbase + j * 16 + s;
            tb[j] = tB[mcol[j]];
            lb[j] = labels[mcol[j]];
        }
        float colE[4] = {0.f, 0.f, 0.f, 0.f}, colT[4] = {0.f, 0.f, 0.f, 0.f};

        float* rsE = rsum_e + z * B_SZ;
        float* rsT = rsum_t + z * B_SZ;
        float* csE = csum_e + z * B_SZ;
        float* csT = csum_t + z * B_SZ;

        #pragma unroll
        for (int ii = 0; ii < 2; ++ii) {
            int nb = rowbase + ii * 16 + q * 4;   // this lane's 4 C rows
            float cta[4]; int la[4];
            #pragma unroll
            for (int r = 0; r < 4; ++r) { cta[r] = curv * tA[nb + r]; la[r] = labels[nb + r]; }
            float re[4] = {0.f, 0.f, 0.f, 0.f}, rt[4] = {0.f, 0.f, 0.f, 0.f};
            #pragma unroll
            for (int j = 0; j < 4; ++j) {
                floatx4 a = acc[ii][j];
                #pragma unroll
                for (int r = 0; r < 4; ++r) {
                    float zc = fmaf(-curv, a[r], cta[r] * tb[j]);
                    zc = fmaxf(zc, 1.0f + 1e-8f);
                    float lz = __log2f(zc);
                    float e = __builtin_amdgcn_exp2f(fmaf(c2, lz, sh2p));
                    float tl2 = (la[r] == lb[j]) ? fmaf(c1, lz, c1) : 0.0f;
                    re[r] += e; rt[r] += tl2;
                    colE[j] += e; colT[j] += tl2;
                }
            }
            #pragma unroll
            for (int r = 0; r < 4; ++r) {
                #pragma unroll
                for (int m = 1; m <= 8; m <<= 1) {
                    re[r] += __shfl_xor(re[r], m);
                    rt[r] += __shfl_xor(rt[r], m);
                }
            }
            #pragma unroll
            for (int r = 0; r < 4; ++r) {
                if (s == r) {
                    atomicAdd(&rsE[nb + r], re[r]);
                    atomicAdd(&rsT[nb + r], rt[r]);
                }
            }
        }
        #pragma unroll
        for (int j = 0; j < 4; ++j) {
            colE[j] += __shfl_xor(colE[j], 16); colE[j] += __shfl_xor(colE[j], 32);
            colT[j] += __shfl_xor(colT[j], 16); colT[j] += __shfl_xor(colT[j], 32);
            if (q == 0) {
                atomicAdd(&csE[mcol[j]], colE[j]);
                atomicAdd(&csT[mcol[j]], colT[j]);
            }
        }
        // next tile's step 0: lgkmcnt(0) + vmcnt(2) + barrier resync.
    }
#undef KSTEP
#undef TILE_PTRS
}

// ---- parallel finalize: 16 blocks, device-scope atomic accumulation; last
//      block (done counter) writes out. atomicAdd(p,0) read avoids stale L2. ----
__global__ __launch_bounds__(256) void finalize_kernel(
    const float* __restrict__ rsum_e, const float* __restrict__ rsum_t,
    const float* __restrict__ csum_e, const float* __restrict__ csum_t,
    const int* __restrict__ labels, const int* __restrict__ hist,
    const float* __restrict__ ent_partial,
    float* __restrict__ ce_acc, float* __restrict__ ent_acc,
    int* __restrict__ done, float* __restrict__ out) {
    __shared__ float red[4], red2[4];
    int b = blockIdx.x, tid = threadIdx.x;
    int n = b * 256 + tid;                 // covers 0..4095 exactly
    float Sn = (float)hist[labels[n]];
    float part = 0.0f;
    #pragma unroll
    for (int p = 0; p < 3; ++p) {
        part += Sn * (__logf(rsum_e[p * B_SZ + n]) - SHIFT) - rsum_t[p * B_SZ + n];
        part += Sn * (__logf(csum_e[p * B_SZ + n]) - SHIFT) - csum_t[p * B_SZ + n];
    }
    float ep = (b < 4) ? ent_partial[b * 256 + tid] : 0.0f;
    #pragma unroll
    for (int m = 1; m < 64; m <<= 1) {
        part += __shfl_xor(part, m);
        ep   += __shfl_xor(ep, m);
    }
    if ((tid & 63) == 0) { red[tid >> 6] = part; red2[tid >> 6] = ep; }
    __syncthreads();
    if (tid == 0) {
        atomicAdd(ce_acc, red[0] + red[1] + red[2] + red[3]);
        atomicAdd(ent_acc, red2[0] + red2[1] + red2[2] + red2[3]);
        __threadfence();
        if (atomicAdd(done, 1) == 15) {        // last of 16 blocks
            float ce = atomicAdd(ce_acc, 0.0f);    // coherent read
            float ent = atomicAdd(ent_acc, 0.0f);
            float contr = ce / (6.0f * (float)B_SZ);
            ent /= (float)B_SZ;
            out[0] = contr + 0.2f * ent;
            out[1] = contr;
            out[2] = ent;
        }
    }
}

// ---- workspace layout (bytes) ----
//   0       : fp8 feats (K-interleaved), 3*4096*512 = 6,291,456
//   6291456 : times[3][4096] f32   (49,152)
//   6340608 : rsum_e[12288 f]  \
//   6389760 : rsum_t           | zero region: 49155 floats
//   6438912 : csum_e           | (incl. ce_acc, ent_acc, done)
//   6488064 : csum_t           |
//   6537216 : ce_acc f32; 6537220: ent_acc f32; 6537224: done i32
//   6537228 : ent_partial[1024] f32 (every slot written by its dna block)
//   6541324 : hist[512] int (fully written by prep block 0)
extern "C" void kernel_launch(void* const* d_in, const int* in_sizes, int n_in,
                              void* d_out, int out_size, void* d_ws, size_t ws_size,
                              hipStream_t stream) {
    const float* img    = (const float*)d_in[0];
    const float* dna    = (const float*)d_in[1];
    const float* txt    = (const float*)d_in[2];
    const int*   labels = (const int*)d_in[3];
    const float* ls     = (const float*)d_in[4];
    const float* curv   = (const float*)d_in[5];

    char* ws = (char*)d_ws;
    u8*    f8     = (u8*)ws;
    float* times  = (float*)(ws + 6291456);
    float* rsum_e = (float*)(ws + 6340608);
    float* rsum_t = (float*)(ws + 6389760);
    float* csum_e = (float*)(ws + 6438912);
    float* csum_t = (float*)(ws + 6488064);
    float* ce_acc = (float*)(ws + 6537216);
    float* ent_acc= (float*)(ws + 6537220);
    int*   done   = (int*)  (ws + 6537224);
    float* ent_p  = (float*)(ws + 6537228);
    int*   hist   = (int*)  (ws + 6541324);

    prep_kernel<<<3072, 256, 0, stream>>>(img, dna, txt, curv, labels, hist,
                                          f8, times, rsum_e, ent_p);
    gemm_epi_kernel<<<512, 512, 0, stream>>>(f8, times, labels, ls, curv,
                                             rsum_e, rsum_t, csum_e, csum_t);
    finalize_kernel<<<16, 256, 0, stream>>>(rsum_e, rsum_t, csum_e, csum_t,
                                            labels, hist, ent_p,
                                            ce_acc, ent_acc, done, (float*)d_out);
}